// Round 18
// baseline (112.450 us; speedup 1.0000x reference)
//
#include <hip/hip_runtime.h>
#include <stdint.h>

#define BUK 782        // ceil(100000 / 128) src buckets
#define CAP 6912       // per-bucket region capacity (mean ~6246)
#define CH  10240      // edges per passA block -> 625 blocks (1.22 dispatch waves @ 2 blk/CU)
#define GRP 5          // int4 groups per thread (GRP*4*512 = CH)
#define SENTK 0xFFFFFFFFu

__device__ __forceinline__ uint32_t rotl32(uint32_t x, int r) { return (x << r) | (x >> (32 - r)); }

// JAX threefry2x32, key=(0,42), counts x=(0,i); partitionable bits = out0^out1  (validated absmax=0)
__device__ __forceinline__ uint32_t threefry_bits(uint32_t i) {
  const uint32_t k0 = 0u, k1 = 42u;
  const uint32_t k2 = k0 ^ k1 ^ 0x1BD11BDAu;
  uint32_t x0 = k0;
  uint32_t x1 = i + k1;
#define TF_R(r) { x0 += x1; x1 = rotl32(x1, r); x1 ^= x0; }
  TF_R(13) TF_R(15) TF_R(26) TF_R(6)   x0 += k1; x1 += k2 + 1u;
  TF_R(17) TF_R(29) TF_R(16) TF_R(24)  x0 += k2; x1 += k0 + 2u;
  TF_R(13) TF_R(15) TF_R(26) TF_R(6)   x0 += k0; x1 += k1 + 3u;
  TF_R(17) TF_R(29) TF_R(16) TF_R(24)  x0 += k1; x1 += k2 + 4u;
  TF_R(13) TF_R(15) TF_R(26) TF_R(6)   x0 += k2; x1 += k0 + 5u;
#undef TF_R
  return x0 ^ x1;
}

__device__ __forceinline__ bool keep_edge(uint32_t i, float kp) {
  uint32_t bits = threefry_bits(i);
  float u = __uint_as_float((bits >> 9) | 0x3f800000u) - 1.0f;
  return u < kp;
}

__device__ __forceinline__ float keep_prob(const float* pp) {
  double pd = (double)pp[0];
  return (float)(1.0 / (1.0 + exp(-pd)));
}

// inclusive wave scan (64 lanes) via shfl_up
__device__ __forceinline__ uint32_t wave_incl_scan(uint32_t v, int lane) {
#pragma unroll
  for (int off = 1; off < 64; off <<= 1) {
    uint32_t t = (uint32_t)__shfl_up((int)v, off, 64);
    if (lane >= off) v += t;
  }
  return v;
}

// ---- VALU-pipe xor-shuffle: DPP for j<16, ds for 16/32 ----
template <int J>
__device__ __forceinline__ uint32_t xshf(uint32_t v, int lane) {
  if constexpr (J == 1) {
    return (uint32_t)__builtin_amdgcn_mov_dpp((int)v, 0xB1, 0xF, 0xF, true);  // quad_perm(1,0,3,2)
  } else if constexpr (J == 2) {
    return (uint32_t)__builtin_amdgcn_mov_dpp((int)v, 0x4E, 0xF, 0xF, true);  // quad_perm(2,3,0,1)
  } else if constexpr (J == 4 || J == 8) {
    uint32_t up = (uint32_t)__builtin_amdgcn_mov_dpp((int)v, 0x100 | J, 0xF, 0xF, true);
    uint32_t dn = (uint32_t)__builtin_amdgcn_mov_dpp((int)v, 0x110 | J, 0xF, 0xF, true);
    return (lane & J) ? dn : up;
  } else {
    return (uint32_t)__shfl_xor((int)v, J, 64);
  }
}

__device__ __forceinline__ void cex(uint32_t& v, uint32_t o, bool takeMin) {
  uint32_t mn = v < o ? v : o, mx = v < o ? o : v;
  v = takeMin ? mn : mx;
}
template <int J>
__device__ __forceinline__ void ce1(uint32_t& v, bool takeMin, int lane) {
  cex(v, xshf<J>(v, lane), takeMin);
}

__device__ __forceinline__ uint32_t bitonic64(uint32_t v, int lane) {
#define BS1(J, K) ce1<J>(v, ((lane & (J)) == 0) == ((lane & (K)) == 0), lane)
  BS1(1, 2);
  BS1(2, 4); BS1(1, 4);
  BS1(4, 8); BS1(2, 8); BS1(1, 8);
  BS1(8, 16); BS1(4, 16); BS1(2, 16); BS1(1, 16);
  BS1(16, 32); BS1(8, 32); BS1(4, 32); BS1(2, 32); BS1(1, 32);
  ce1<32>(v, (lane & 32) == 0, lane); ce1<16>(v, (lane & 16) == 0, lane);
  ce1<8>(v, (lane & 8) == 0, lane);   ce1<4>(v, (lane & 4) == 0, lane);
  ce1<2>(v, (lane & 2) == 0, lane);   ce1<1>(v, (lane & 1) == 0, lane);
#undef BS1
  return v;
}

__device__ __forceinline__ void bitonic128(uint32_t& v0, uint32_t& v1, int lane) {
#define BS2(J, K) { bool tm = ((lane & (J)) == 0) == ((lane & (K)) == 0); ce1<J>(v0, tm, lane); ce1<J>(v1, tm, lane); }
  BS2(1, 2);
  BS2(2, 4); BS2(1, 4);
  BS2(4, 8); BS2(2, 8); BS2(1, 8);
  BS2(8, 16); BS2(4, 16); BS2(2, 16); BS2(1, 16);
  BS2(16, 32); BS2(8, 32); BS2(4, 32); BS2(2, 32); BS2(1, 32);
#undef BS2
  ce1<32>(v0, (lane & 32) == 0, lane); ce1<32>(v1, (lane & 32) != 0, lane);
  ce1<16>(v0, (lane & 16) == 0, lane); ce1<16>(v1, (lane & 16) != 0, lane);
  ce1<8>(v0, (lane & 8) == 0, lane);   ce1<8>(v1, (lane & 8) != 0, lane);
  ce1<4>(v0, (lane & 4) == 0, lane);   ce1<4>(v1, (lane & 4) != 0, lane);
  ce1<2>(v0, (lane & 2) == 0, lane);   ce1<2>(v1, (lane & 2) != 0, lane);
  ce1<1>(v0, (lane & 1) == 0, lane);   ce1<1>(v1, (lane & 1) != 0, lane);
  { uint32_t lo = v0 < v1 ? v0 : v1, hi = v0 < v1 ? v1 : v0; v0 = lo; v1 = hi; }
  ce1<32>(v0, (lane & 32) == 0, lane); ce1<32>(v1, (lane & 32) == 0, lane);
  ce1<16>(v0, (lane & 16) == 0, lane); ce1<16>(v1, (lane & 16) == 0, lane);
  ce1<8>(v0, (lane & 8) == 0, lane);   ce1<8>(v1, (lane & 8) == 0, lane);
  ce1<4>(v0, (lane & 4) == 0, lane);   ce1<4>(v1, (lane & 4) == 0, lane);
  ce1<2>(v0, (lane & 2) == 0, lane);   ce1<2>(v1, (lane & 2) == 0, lane);
  ce1<1>(v0, (lane & 1) == 0, lane);   ce1<1>(v1, (lane & 1) == 0, lane);
}

// ---- pass A: R17-validated v2 structure, CH=10240 (625 blocks -> 1.22 dispatch waves) ----
__global__ __launch_bounds__(512) void passA_k(const int* __restrict__ a0,
                                               const int* __restrict__ an,
                                               int e0, int en, const float* __restrict__ pp,
                                               uint32_t* __restrict__ cur_g,
                                               uint32_t* __restrict__ bkt) {
  __shared__ uint32_t stageK[CH];   // 40 KB
  __shared__ uint16_t stageB[CH];   // 20 KB
  __shared__ uint32_t cntA[784];
  __shared__ uint32_t loA[784];
  __shared__ uint32_t gb[784];
  __shared__ uint32_t sums[512];

  float kp = keep_prob(pp);
  int tid = threadIdx.x;
  int total = e0 + en;
  int base = blockIdx.x * CH;

  uint32_t key[4 * GRP];
  uint32_t bkid[4 * GRP];

  for (int t = tid; t < 784; t += 512) cntA[t] = 0;
  __syncthreads();

  // phase 1: GRP groups of 4 consecutive edges per thread, int4 loads + LDS histogram
#pragma unroll
  for (int k = 0; k < GRP; k++) {
    int g = base + 4 * (k * 512 + tid);
    int s4[4], d4[4];
    bool have = false;
    if (g + 3 < e0) {
      int4 sv = *reinterpret_cast<const int4*>(&a0[g]);
      int4 dv = *reinterpret_cast<const int4*>(&a0[e0 + g]);
      s4[0] = sv.x; s4[1] = sv.y; s4[2] = sv.z; s4[3] = sv.w;
      d4[0] = dv.x; d4[1] = dv.y; d4[2] = dv.z; d4[3] = dv.w;
      have = true;
    } else if (g >= e0 && g + 3 < total) {
      int j = g - e0;
      int4 sv = *reinterpret_cast<const int4*>(&an[j]);
      int4 dv = *reinterpret_cast<const int4*>(&an[en + j]);
      s4[0] = sv.x; s4[1] = sv.y; s4[2] = sv.z; s4[3] = sv.w;
      d4[0] = dv.x; d4[1] = dv.y; d4[2] = dv.z; d4[3] = dv.w;
      have = true;
    } else if (g < total) {
      for (int e = 0; e < 4; e++) {
        int idx = g + e;
        if (idx < total) {
          if (idx < e0) { s4[e] = a0[idx]; d4[e] = a0[e0 + idx]; }
          else          { int j = idx - e0; s4[e] = an[j]; d4[e] = an[en + j]; }
        } else { s4[e] = -1; d4[e] = 0; }
      }
      have = true;
    }
#pragma unroll
    for (int e = 0; e < 4; e++) {
      int idx = g + e;
      uint32_t ky = SENTK, b_ = SENTK;
      if (have && idx < total && s4[e] >= 0) {
        bool keep = (idx < e0) ? keep_edge((uint32_t)idx, kp) : true;
        if (keep) {
          uint32_t us = (uint32_t)s4[e];
          b_ = us >> 7;
          if (b_ < BUK) ky = ((us & 127u) << 17) | (uint32_t)d4[e];
          else b_ = SENTK;
        }
      }
      key[k * 4 + e] = ky;
      bkid[k * 4 + e] = b_;
      if (b_ != SENTK) atomicAdd(&cntA[b_], 1u);
    }
  }
  __syncthreads();

  // phase 2: exclusive scan over 784 bins (pairs -> 392 sums, Hillis over 512)
  {
    uint32_t s2 = 0;
    if (tid < 392) s2 = cntA[2 * tid] + cntA[2 * tid + 1];
    sums[tid] = s2;
    __syncthreads();
    for (int off = 1; off < 512; off <<= 1) {
      uint32_t a = (tid >= off) ? sums[tid - off] : 0u;
      __syncthreads();
      sums[tid] += a;
      __syncthreads();
    }
    if (tid < 392) {
      uint32_t b0 = sums[tid] - s2;
      loA[2 * tid] = b0;
      loA[2 * tid + 1] = b0 + cntA[2 * tid];
    }
  }
  __syncthreads();
  for (int t = tid; t < 784; t += 512) gb[t] = loA[t];
  __syncthreads();

  // phase 3: LDS counting-scatter into bucket-major staging
#pragma unroll
  for (int k = 0; k < 4 * GRP; k++) {
    uint32_t b_ = bkid[k];
    if (b_ != SENTK) {
      uint32_t p = atomicAdd(&gb[b_], 1u);
      stageK[p] = key[k];
      stageB[p] = (uint16_t)b_;
    }
  }
  __syncthreads();

  // phase 4: per-bucket global reservation (unpadded, as in v2)
  for (int t = tid; t < BUK; t += 512) {
    uint32_t c = cntA[t];
    gb[t] = c ? atomicAdd(&cur_g[t], c) : 0u;
  }
  __syncthreads();

  // phase 5: staged-order cooperative flush (coalesced bucket runs)
  uint32_t kept = sums[511];
  for (uint32_t i = tid; i < kept; i += 512) {
    uint32_t b_ = (uint32_t)stageB[i];
    uint32_t addr = gb[b_] + (i - loA[b_]);
    if (addr < CAP) bkt[(size_t)b_ * CAP + addr] = stageK[i];
  }
}

// ---- pass B v5 (R17-validated): uint4 read -> regs; reg hist+scatter; DPP-bitonic; dedup ----
__global__ __launch_bounds__(512) void passB_k(uint32_t* __restrict__ bkt,
                                               const uint32_t* __restrict__ cur_g,
                                               uint32_t* __restrict__ ucnt) {
  __shared__ uint32_t lin[CAP];                 // 27 KB
  __shared__ uint32_t c128[128], lo128[128], cur128[128];
  __shared__ uint32_t u128[128], uo128[128];

  int b = blockIdx.x, tid = threadIdx.x;
  int wid = tid >> 6, lane = tid & 63;
  uint32_t len = cur_g[b];
  if (len > CAP) len = CAP;
  uint32_t* seg = bkt + (size_t)b * CAP;

  if (tid < 128) c128[tid] = 0;
  __syncthreads();

  // single vectorized read into registers (<= 16 values/thread)
  uint32_t rv[16];
#pragma unroll
  for (int k = 0; k < 4; k++) {
    uint32_t i4 = 4u * (uint32_t)(k * 512 + tid);
    if (i4 + 3 < len) {
      uint4 v = *reinterpret_cast<const uint4*>(&seg[i4]);
      rv[4 * k] = v.x; rv[4 * k + 1] = v.y; rv[4 * k + 2] = v.z; rv[4 * k + 3] = v.w;
    } else {
#pragma unroll
      for (int e = 0; e < 4; e++) rv[4 * k + e] = (i4 + e < len) ? seg[i4 + e] : SENTK;
    }
  }

  // histogram from registers
#pragma unroll
  for (int k = 0; k < 16; k++)
    if (rv[k] != SENTK) atomicAdd(&c128[rv[k] >> 17], 1u);
  __syncthreads();

  // wave-0 shuffle scan of 128 counts -> lo128/cur128 (exclusive)
  if (wid == 0) {
    uint32_t c0 = c128[2 * lane], c1 = c128[2 * lane + 1];
    uint32_t s = c0 + c1;
    uint32_t inc = wave_incl_scan(s, lane);
    uint32_t ex = inc - s;
    lo128[2 * lane] = ex;       lo128[2 * lane + 1] = ex + c0;
    cur128[2 * lane] = ex;      cur128[2 * lane + 1] = ex + c0;
  }
  __syncthreads();

  // counting-scatter from registers
#pragma unroll
  for (int k = 0; k < 16; k++)
    if (rv[k] != SENTK) lin[atomicAdd(&cur128[rv[k] >> 17], 1u)] = rv[k];
  __syncthreads();

  // per-wave sub-bin sort + dedup-compact (regions disjoint across waves)
  for (int s = wid; s < 128; s += 8) {
    uint32_t L = c128[s], sb = lo128[s];
    if (L > 1u && L <= 64u) {
      uint32_t v = (lane < (int)L) ? lin[sb + lane] : SENTK;
      v = bitonic64(v, lane);
      if (lane < (int)L) lin[sb + lane] = v;
    } else if (L > 64u && L <= 128u) {
      uint32_t v0 = (lane < (int)L) ? lin[sb + lane] : SENTK;
      uint32_t v1 = (64 + lane < (int)L) ? lin[sb + 64 + lane] : SENTK;
      bitonic128(v0, v1, lane);
      if (lane < (int)L) lin[sb + lane] = v0;
      if (64 + lane < (int)L) lin[sb + 64 + lane] = v1;
    } else if (L > 128u) {
      // never expected (mean 48.8); rank-sort via dead global seg region
      uint32_t* gsc = seg + sb;
      for (uint32_t i0 = lane; i0 < L; i0 += 64) {
        uint32_t x = lin[sb + i0];
        uint32_t pos = 0;
        for (uint32_t j = 0; j < L; j++) {
          uint32_t y = lin[sb + j];
          pos += (y < x || (y == x && j < i0)) ? 1u : 0u;
        }
        gsc[pos] = x;
      }
      asm volatile("s_waitcnt vmcnt(0)" ::: "memory");
      for (uint32_t i0 = lane; i0 < L; i0 += 64) lin[sb + i0] = gsc[i0];
    }
    // dedup-compact within sub-bin
    uint32_t ub = 0;
    for (uint32_t t = 0; t < L; t += 64) {
      uint32_t i = t + lane;
      bool valid = i < L;
      uint32_t x = valid ? lin[sb + i] : 0u;
      uint32_t prev = valid ? lin[sb + (i == 0 ? 0 : i - 1)] : 0u;
      bool uniq = valid && (i == 0 || prev != x);
      unsigned long long ball = __ballot(uniq ? 1 : 0);
      uint32_t rank = (uint32_t)__popcll(ball & ((1ull << lane) - 1ull));
      if (uniq) lin[sb + ub + rank] = x;
      ub += (uint32_t)__popcll(ball);
    }
    if (lane == 0) u128[s] = ub;
  }
  __syncthreads();

  // wave-0 shuffle scan of unique counts -> uo128 (exclusive) + ucnt[b]
  if (wid == 0) {
    uint32_t c0 = u128[2 * lane], c1 = u128[2 * lane + 1];
    uint32_t s = c0 + c1;
    uint32_t inc = wave_incl_scan(s, lane);
    uint32_t ex = inc - s;
    uo128[2 * lane] = ex;       uo128[2 * lane + 1] = ex + c0;
    if (lane == 63) ucnt[b] = inc;
  }
  __syncthreads();

  // copy compacted uniques to seg front (sub-bin order = key order)
  for (int s = wid; s < 128; s += 8) {
    uint32_t u = u128[s], sb = lo128[s], ob = uo128[s];
    for (uint32_t k2 = lane; k2 < u; k2 += 64) seg[ob + k2] = lin[sb + k2];
  }
}

// ---- single-wave exclusive scan over 782 unique counts ----
__global__ __launch_bounds__(64) void uscan_k(const uint32_t* __restrict__ ucnt,
                                              uint32_t* __restrict__ uoff) {
  int lane = threadIdx.x;
  uint32_t c[13];
  uint32_t s = 0;
#pragma unroll
  for (int j = 0; j < 13; j++) {
    int idx = lane * 13 + j;
    c[j] = (idx < BUK) ? ucnt[idx] : 0u;
    s += c[j];
  }
  uint32_t inc = wave_incl_scan(s, lane);
  uint32_t ex = inc - s;
#pragma unroll
  for (int j = 0; j < 13; j++) {
    int idx = lane * 13 + j;
    if (idx < BUK) uoff[idx] = ex;
    ex += c[j];
  }
  if (lane == 63) uoff[BUK] = ex;
}

// ---- pass C: expand deduped keys to the two output rows ----
__global__ __launch_bounds__(256) void passC_k(const uint32_t* __restrict__ bkt,
                                               const uint32_t* __restrict__ uoff,
                                               int* __restrict__ out, int oute) {
  int b = blockIdx.x;
  uint32_t lo = uoff[b], u = uoff[b + 1] - lo;
  const uint32_t* seg = bkt + (size_t)b * CAP;
  for (uint32_t k = threadIdx.x; k < u; k += 256) {
    uint32_t key = seg[k];
    out[lo + k] = (int)((uint32_t)(b << 7) | (key >> 17));
    out[oute + lo + k] = (int)(key & 0x1FFFFu);
  }
}

// ---- fill only the invalid tail with -1 ----
__global__ void tail_k(const uint32_t* __restrict__ uoff, int* __restrict__ out, int oute) {
  uint32_t total = uoff[BUK];
  for (uint32_t i = blockIdx.x * blockDim.x + threadIdx.x + total; i < (uint32_t)oute;
       i += gridDim.x * blockDim.x) {
    out[i] = -1;
    out[oute + i] = -1;
  }
}

extern "C" void kernel_launch(void* const* d_in, const int* in_sizes, int n_in,
                              void* d_out, int out_size, void* d_ws, size_t ws_size,
                              hipStream_t stream) {
  const int* a0 = (const int*)d_in[0];
  const int* an = (const int*)d_in[1];
  const float* pp = (const float*)d_in[3];
  int e0 = in_sizes[0] / 2;
  int en = in_sizes[1] / 2;
  int M = e0 + en;
  int oute = out_size / 2;

  uint8_t* wbase = (uint8_t*)d_ws;
  size_t o = 0;
  auto nxt = [&](size_t bytes) -> void* {
    void* p = wbase + o;
    o = (o + bytes + 255) & ~(size_t)255;
    return p;
  };
  uint32_t* cur_g = (uint32_t*)nxt((size_t)BUK * 4);
  uint32_t* ucnt  = (uint32_t*)nxt((size_t)BUK * 4);
  uint32_t* uoff  = (uint32_t*)nxt((size_t)(BUK + 1) * 4);
  uint32_t* bkt   = (uint32_t*)nxt((size_t)BUK * CAP * 4);  // ~21.6 MB

  int ablocks = (M + CH - 1) / CH;  // 625

  hipMemsetAsync(cur_g, 0, (size_t)BUK * 4, stream);
  passA_k<<<ablocks, 512, 0, stream>>>(a0, an, e0, en, pp, cur_g, bkt);
  passB_k<<<BUK, 512, 0, stream>>>(bkt, cur_g, ucnt);
  uscan_k<<<1, 64, 0, stream>>>(ucnt, uoff);
  passC_k<<<BUK, 256, 0, stream>>>(bkt, uoff, (int*)d_out, oute);
  tail_k<<<1024, 256, 0, stream>>>(uoff, (int*)d_out, oute);
}

// Round 19
// 107.340 us; speedup vs baseline: 1.0476x; 1.0476x over previous
//
#include <hip/hip_runtime.h>
#include <stdint.h>

#define BUK 782        // ceil(100000 / 128) src buckets
#define CAP 6912       // per-bucket region capacity (mean ~6246)
#define CH  8192       // edges per passA block (R17-validated sweet spot)
#define SENTK 0xFFFFFFFFu

__device__ __forceinline__ uint32_t rotl32(uint32_t x, int r) { return (x << r) | (x >> (32 - r)); }

// JAX threefry2x32, key=(0,42), counts x=(0,i); partitionable bits = out0^out1  (validated absmax=0)
__device__ __forceinline__ uint32_t threefry_bits(uint32_t i) {
  const uint32_t k0 = 0u, k1 = 42u;
  const uint32_t k2 = k0 ^ k1 ^ 0x1BD11BDAu;
  uint32_t x0 = k0;
  uint32_t x1 = i + k1;
#define TF_R(r) { x0 += x1; x1 = rotl32(x1, r); x1 ^= x0; }
  TF_R(13) TF_R(15) TF_R(26) TF_R(6)   x0 += k1; x1 += k2 + 1u;
  TF_R(17) TF_R(29) TF_R(16) TF_R(24)  x0 += k2; x1 += k0 + 2u;
  TF_R(13) TF_R(15) TF_R(26) TF_R(6)   x0 += k0; x1 += k1 + 3u;
  TF_R(17) TF_R(29) TF_R(16) TF_R(24)  x0 += k1; x1 += k2 + 4u;
  TF_R(13) TF_R(15) TF_R(26) TF_R(6)   x0 += k2; x1 += k0 + 5u;
#undef TF_R
  return x0 ^ x1;
}

__device__ __forceinline__ bool keep_edge(uint32_t i, float kp) {
  uint32_t bits = threefry_bits(i);
  float u = __uint_as_float((bits >> 9) | 0x3f800000u) - 1.0f;
  return u < kp;
}

__device__ __forceinline__ float keep_prob(const float* pp) {
  double pd = (double)pp[0];
  return (float)(1.0 / (1.0 + exp(-pd)));
}

// inclusive wave scan (64 lanes) via shfl_up
__device__ __forceinline__ uint32_t wave_incl_scan(uint32_t v, int lane) {
#pragma unroll
  for (int off = 1; off < 64; off <<= 1) {
    uint32_t t = (uint32_t)__shfl_up((int)v, off, 64);
    if (lane >= off) v += t;
  }
  return v;
}

// ---- VALU-pipe xor-shuffle: DPP for j<16, ds for 16/32 ----
template <int J>
__device__ __forceinline__ uint32_t xshf(uint32_t v, int lane) {
  if constexpr (J == 1) {
    return (uint32_t)__builtin_amdgcn_mov_dpp((int)v, 0xB1, 0xF, 0xF, true);  // quad_perm(1,0,3,2)
  } else if constexpr (J == 2) {
    return (uint32_t)__builtin_amdgcn_mov_dpp((int)v, 0x4E, 0xF, 0xF, true);  // quad_perm(2,3,0,1)
  } else if constexpr (J == 4 || J == 8) {
    uint32_t up = (uint32_t)__builtin_amdgcn_mov_dpp((int)v, 0x100 | J, 0xF, 0xF, true);
    uint32_t dn = (uint32_t)__builtin_amdgcn_mov_dpp((int)v, 0x110 | J, 0xF, 0xF, true);
    return (lane & J) ? dn : up;
  } else {
    return (uint32_t)__shfl_xor((int)v, J, 64);
  }
}

__device__ __forceinline__ void cex(uint32_t& v, uint32_t o, bool takeMin) {
  uint32_t mn = v < o ? v : o, mx = v < o ? o : v;
  v = takeMin ? mn : mx;
}
template <int J>
__device__ __forceinline__ void ce1(uint32_t& v, bool takeMin, int lane) {
  cex(v, xshf<J>(v, lane), takeMin);
}

__device__ __forceinline__ uint32_t bitonic64(uint32_t v, int lane) {
#define BS1(J, K) ce1<J>(v, ((lane & (J)) == 0) == ((lane & (K)) == 0), lane)
  BS1(1, 2);
  BS1(2, 4); BS1(1, 4);
  BS1(4, 8); BS1(2, 8); BS1(1, 8);
  BS1(8, 16); BS1(4, 16); BS1(2, 16); BS1(1, 16);
  BS1(16, 32); BS1(8, 32); BS1(4, 32); BS1(2, 32); BS1(1, 32);
  ce1<32>(v, (lane & 32) == 0, lane); ce1<16>(v, (lane & 16) == 0, lane);
  ce1<8>(v, (lane & 8) == 0, lane);   ce1<4>(v, (lane & 4) == 0, lane);
  ce1<2>(v, (lane & 2) == 0, lane);   ce1<1>(v, (lane & 1) == 0, lane);
#undef BS1
  return v;
}

__device__ __forceinline__ void bitonic128(uint32_t& v0, uint32_t& v1, int lane) {
#define BS2(J, K) { bool tm = ((lane & (J)) == 0) == ((lane & (K)) == 0); ce1<J>(v0, tm, lane); ce1<J>(v1, tm, lane); }
  BS2(1, 2);
  BS2(2, 4); BS2(1, 4);
  BS2(4, 8); BS2(2, 8); BS2(1, 8);
  BS2(8, 16); BS2(4, 16); BS2(2, 16); BS2(1, 16);
  BS2(16, 32); BS2(8, 32); BS2(4, 32); BS2(2, 32); BS2(1, 32);
#undef BS2
  ce1<32>(v0, (lane & 32) == 0, lane); ce1<32>(v1, (lane & 32) != 0, lane);
  ce1<16>(v0, (lane & 16) == 0, lane); ce1<16>(v1, (lane & 16) != 0, lane);
  ce1<8>(v0, (lane & 8) == 0, lane);   ce1<8>(v1, (lane & 8) != 0, lane);
  ce1<4>(v0, (lane & 4) == 0, lane);   ce1<4>(v1, (lane & 4) != 0, lane);
  ce1<2>(v0, (lane & 2) == 0, lane);   ce1<2>(v1, (lane & 2) != 0, lane);
  ce1<1>(v0, (lane & 1) == 0, lane);   ce1<1>(v1, (lane & 1) != 0, lane);
  { uint32_t lo = v0 < v1 ? v0 : v1, hi = v0 < v1 ? v1 : v0; v0 = lo; v1 = hi; }
  ce1<32>(v0, (lane & 32) == 0, lane); ce1<32>(v1, (lane & 32) == 0, lane);
  ce1<16>(v0, (lane & 16) == 0, lane); ce1<16>(v1, (lane & 16) == 0, lane);
  ce1<8>(v0, (lane & 8) == 0, lane);   ce1<8>(v1, (lane & 8) == 0, lane);
  ce1<4>(v0, (lane & 4) == 0, lane);   ce1<4>(v1, (lane & 4) == 0, lane);
  ce1<2>(v0, (lane & 2) == 0, lane);   ce1<2>(v1, (lane & 2) == 0, lane);
  ce1<1>(v0, (lane & 1) == 0, lane);   ce1<1>(v1, (lane & 1) == 0, lane);
}

// ---- pass A: LITERAL R17-validated v2 (57.5us, WRITE 35.7MB) ----
__global__ __launch_bounds__(512) void passA_k(const int* __restrict__ a0,
                                               const int* __restrict__ an,
                                               int e0, int en, const float* __restrict__ pp,
                                               uint32_t* __restrict__ cur_g,
                                               uint32_t* __restrict__ bkt) {
  __shared__ uint32_t stageK[CH];
  __shared__ uint16_t stageB[CH];
  __shared__ uint32_t cntA[784];
  __shared__ uint32_t loA[784];
  __shared__ uint32_t gb[784];
  __shared__ uint32_t sums[512];

  float kp = keep_prob(pp);
  int tid = threadIdx.x;
  int total = e0 + en;
  int base = blockIdx.x * CH;

  uint32_t key[16];
  uint32_t bkid[16];

  for (int t = tid; t < 784; t += 512) cntA[t] = 0;
  __syncthreads();

  // phase 1: 4 groups of 4 consecutive edges per thread, int4 loads + LDS histogram
#pragma unroll
  for (int k = 0; k < 4; k++) {
    int g = base + 4 * (k * 512 + tid);
    int s4[4], d4[4];
    bool have = false;
    if (g + 3 < e0) {
      int4 sv = *reinterpret_cast<const int4*>(&a0[g]);
      int4 dv = *reinterpret_cast<const int4*>(&a0[e0 + g]);
      s4[0] = sv.x; s4[1] = sv.y; s4[2] = sv.z; s4[3] = sv.w;
      d4[0] = dv.x; d4[1] = dv.y; d4[2] = dv.z; d4[3] = dv.w;
      have = true;
    } else if (g >= e0 && g + 3 < total) {
      int j = g - e0;
      int4 sv = *reinterpret_cast<const int4*>(&an[j]);
      int4 dv = *reinterpret_cast<const int4*>(&an[en + j]);
      s4[0] = sv.x; s4[1] = sv.y; s4[2] = sv.z; s4[3] = sv.w;
      d4[0] = dv.x; d4[1] = dv.y; d4[2] = dv.z; d4[3] = dv.w;
      have = true;
    } else if (g < total) {
      for (int e = 0; e < 4; e++) {
        int idx = g + e;
        if (idx < total) {
          if (idx < e0) { s4[e] = a0[idx]; d4[e] = a0[e0 + idx]; }
          else          { int j = idx - e0; s4[e] = an[j]; d4[e] = an[en + j]; }
        } else { s4[e] = -1; d4[e] = 0; }
      }
      have = true;
    }
#pragma unroll
    for (int e = 0; e < 4; e++) {
      int idx = g + e;
      uint32_t ky = SENTK, b_ = SENTK;
      if (have && idx < total && s4[e] >= 0) {
        bool keep = (idx < e0) ? keep_edge((uint32_t)idx, kp) : true;
        if (keep) {
          uint32_t us = (uint32_t)s4[e];
          b_ = us >> 7;
          if (b_ < BUK) ky = ((us & 127u) << 17) | (uint32_t)d4[e];
          else b_ = SENTK;
        }
      }
      key[k * 4 + e] = ky;
      bkid[k * 4 + e] = b_;
      if (b_ != SENTK) atomicAdd(&cntA[b_], 1u);
    }
  }
  __syncthreads();

  // phase 2: exclusive scan over 784 bins (pairs -> 392 sums, Hillis over 512)
  {
    uint32_t s2 = 0;
    if (tid < 392) s2 = cntA[2 * tid] + cntA[2 * tid + 1];
    sums[tid] = s2;
    __syncthreads();
    for (int off = 1; off < 512; off <<= 1) {
      uint32_t a = (tid >= off) ? sums[tid - off] : 0u;
      __syncthreads();
      sums[tid] += a;
      __syncthreads();
    }
    if (tid < 392) {
      uint32_t b0 = sums[tid] - s2;
      loA[2 * tid] = b0;
      loA[2 * tid + 1] = b0 + cntA[2 * tid];
    }
  }
  __syncthreads();
  for (int t = tid; t < 784; t += 512) gb[t] = loA[t];
  __syncthreads();

  // phase 3: LDS counting-scatter into bucket-major staging
#pragma unroll
  for (int k = 0; k < 16; k++) {
    uint32_t b_ = bkid[k];
    if (b_ != SENTK) {
      uint32_t p = atomicAdd(&gb[b_], 1u);
      stageK[p] = key[k];
      stageB[p] = (uint16_t)b_;
    }
  }
  __syncthreads();

  // phase 4: per-bucket global reservation (unpadded)
  for (int t = tid; t < BUK; t += 512) {
    uint32_t c = cntA[t];
    gb[t] = c ? atomicAdd(&cur_g[t], c) : 0u;
  }
  __syncthreads();

  // phase 5: staged-order cooperative flush (coalesced bucket runs)
  uint32_t kept = sums[511];
  for (uint32_t i = tid; i < kept; i += 512) {
    uint32_t b_ = (uint32_t)stageB[i];
    uint32_t addr = gb[b_] + (i - loA[b_]);
    if (addr < CAP) bkt[(size_t)b_ * CAP + addr] = stageK[i];
  }
}

// ---- pass B v5 (R17-validated ~39us): uint4 read -> regs; reg hist+scatter; DPP-bitonic; dedup ----
__global__ __launch_bounds__(512) void passB_k(uint32_t* __restrict__ bkt,
                                               const uint32_t* __restrict__ cur_g,
                                               uint32_t* __restrict__ ucnt) {
  __shared__ uint32_t lin[CAP];                 // 27 KB
  __shared__ uint32_t c128[128], lo128[128], cur128[128];
  __shared__ uint32_t u128[128], uo128[128];

  int b = blockIdx.x, tid = threadIdx.x;
  int wid = tid >> 6, lane = tid & 63;
  uint32_t len = cur_g[b];
  if (len > CAP) len = CAP;
  uint32_t* seg = bkt + (size_t)b * CAP;

  if (tid < 128) c128[tid] = 0;
  __syncthreads();

  // single vectorized read into registers (<= 16 values/thread)
  uint32_t rv[16];
#pragma unroll
  for (int k = 0; k < 4; k++) {
    uint32_t i4 = 4u * (uint32_t)(k * 512 + tid);
    if (i4 + 3 < len) {
      uint4 v = *reinterpret_cast<const uint4*>(&seg[i4]);
      rv[4 * k] = v.x; rv[4 * k + 1] = v.y; rv[4 * k + 2] = v.z; rv[4 * k + 3] = v.w;
    } else {
#pragma unroll
      for (int e = 0; e < 4; e++) rv[4 * k + e] = (i4 + e < len) ? seg[i4 + e] : SENTK;
    }
  }

  // histogram from registers
#pragma unroll
  for (int k = 0; k < 16; k++)
    if (rv[k] != SENTK) atomicAdd(&c128[rv[k] >> 17], 1u);
  __syncthreads();

  // wave-0 shuffle scan of 128 counts -> lo128/cur128 (exclusive)
  if (wid == 0) {
    uint32_t c0 = c128[2 * lane], c1 = c128[2 * lane + 1];
    uint32_t s = c0 + c1;
    uint32_t inc = wave_incl_scan(s, lane);
    uint32_t ex = inc - s;
    lo128[2 * lane] = ex;       lo128[2 * lane + 1] = ex + c0;
    cur128[2 * lane] = ex;      cur128[2 * lane + 1] = ex + c0;
  }
  __syncthreads();

  // counting-scatter from registers
#pragma unroll
  for (int k = 0; k < 16; k++)
    if (rv[k] != SENTK) lin[atomicAdd(&cur128[rv[k] >> 17], 1u)] = rv[k];
  __syncthreads();

  // per-wave sub-bin sort + dedup-compact (regions disjoint across waves)
  for (int s = wid; s < 128; s += 8) {
    uint32_t L = c128[s], sb = lo128[s];
    if (L > 1u && L <= 64u) {
      uint32_t v = (lane < (int)L) ? lin[sb + lane] : SENTK;
      v = bitonic64(v, lane);
      if (lane < (int)L) lin[sb + lane] = v;
    } else if (L > 64u && L <= 128u) {
      uint32_t v0 = (lane < (int)L) ? lin[sb + lane] : SENTK;
      uint32_t v1 = (64 + lane < (int)L) ? lin[sb + 64 + lane] : SENTK;
      bitonic128(v0, v1, lane);
      if (lane < (int)L) lin[sb + lane] = v0;
      if (64 + lane < (int)L) lin[sb + 64 + lane] = v1;
    } else if (L > 128u) {
      // never expected (mean 48.8); rank-sort via dead global seg region
      uint32_t* gsc = seg + sb;
      for (uint32_t i0 = lane; i0 < L; i0 += 64) {
        uint32_t x = lin[sb + i0];
        uint32_t pos = 0;
        for (uint32_t j = 0; j < L; j++) {
          uint32_t y = lin[sb + j];
          pos += (y < x || (y == x && j < i0)) ? 1u : 0u;
        }
        gsc[pos] = x;
      }
      asm volatile("s_waitcnt vmcnt(0)" ::: "memory");
      for (uint32_t i0 = lane; i0 < L; i0 += 64) lin[sb + i0] = gsc[i0];
    }
    // dedup-compact within sub-bin
    uint32_t ub = 0;
    for (uint32_t t = 0; t < L; t += 64) {
      uint32_t i = t + lane;
      bool valid = i < L;
      uint32_t x = valid ? lin[sb + i] : 0u;
      uint32_t prev = valid ? lin[sb + (i == 0 ? 0 : i - 1)] : 0u;
      bool uniq = valid && (i == 0 || prev != x);
      unsigned long long ball = __ballot(uniq ? 1 : 0);
      uint32_t rank = (uint32_t)__popcll(ball & ((1ull << lane) - 1ull));
      if (uniq) lin[sb + ub + rank] = x;
      ub += (uint32_t)__popcll(ball);
    }
    if (lane == 0) u128[s] = ub;
  }
  __syncthreads();

  // wave-0 shuffle scan of unique counts -> uo128 (exclusive) + ucnt[b]
  if (wid == 0) {
    uint32_t c0 = u128[2 * lane], c1 = u128[2 * lane + 1];
    uint32_t s = c0 + c1;
    uint32_t inc = wave_incl_scan(s, lane);
    uint32_t ex = inc - s;
    uo128[2 * lane] = ex;       uo128[2 * lane + 1] = ex + c0;
    if (lane == 63) ucnt[b] = inc;
  }
  __syncthreads();

  // copy compacted uniques to seg front (sub-bin order = key order)
  for (int s = wid; s < 128; s += 8) {
    uint32_t u = u128[s], sb = lo128[s], ob = uo128[s];
    for (uint32_t k2 = lane; k2 < u; k2 += 64) seg[ob + k2] = lin[sb + k2];
  }
}

// ---- single-wave exclusive scan over 782 unique counts ----
__global__ __launch_bounds__(64) void uscan_k(const uint32_t* __restrict__ ucnt,
                                              uint32_t* __restrict__ uoff) {
  int lane = threadIdx.x;
  uint32_t c[13];
  uint32_t s = 0;
#pragma unroll
  for (int j = 0; j < 13; j++) {
    int idx = lane * 13 + j;
    c[j] = (idx < BUK) ? ucnt[idx] : 0u;
    s += c[j];
  }
  uint32_t inc = wave_incl_scan(s, lane);
  uint32_t ex = inc - s;
#pragma unroll
  for (int j = 0; j < 13; j++) {
    int idx = lane * 13 + j;
    if (idx < BUK) uoff[idx] = ex;
    ex += c[j];
  }
  if (lane == 63) uoff[BUK] = ex;
}

// ---- pass C+tail fused: expand uniques to the two output rows, then fill invalid tail ----
__global__ __launch_bounds__(256) void passCT_k(const uint32_t* __restrict__ bkt,
                                                const uint32_t* __restrict__ uoff,
                                                int* __restrict__ out, int oute) {
  int b = blockIdx.x;
  uint32_t lo = uoff[b], u = uoff[b + 1] - lo;
  const uint32_t* seg = bkt + (size_t)b * CAP;
  for (uint32_t k = threadIdx.x; k < u; k += 256) {
    uint32_t key = seg[k];
    out[lo + k] = (int)((uint32_t)(b << 7) | (key >> 17));
    out[oute + lo + k] = (int)(key & 0x1FFFFu);
  }
  // tail fill: all blocks grid-stride the invalid region [total, oute)
  uint32_t total = uoff[BUK];
  for (uint32_t i = blockIdx.x * 256u + threadIdx.x + total; i < (uint32_t)oute;
       i += (uint32_t)gridDim.x * 256u) {
    out[i] = -1;
    out[oute + i] = -1;
  }
}

extern "C" void kernel_launch(void* const* d_in, const int* in_sizes, int n_in,
                              void* d_out, int out_size, void* d_ws, size_t ws_size,
                              hipStream_t stream) {
  const int* a0 = (const int*)d_in[0];
  const int* an = (const int*)d_in[1];
  const float* pp = (const float*)d_in[3];
  int e0 = in_sizes[0] / 2;
  int en = in_sizes[1] / 2;
  int M = e0 + en;
  int oute = out_size / 2;

  uint8_t* wbase = (uint8_t*)d_ws;
  size_t o = 0;
  auto nxt = [&](size_t bytes) -> void* {
    void* p = wbase + o;
    o = (o + bytes + 255) & ~(size_t)255;
    return p;
  };
  uint32_t* cur_g = (uint32_t*)nxt((size_t)BUK * 4);
  uint32_t* ucnt  = (uint32_t*)nxt((size_t)BUK * 4);
  uint32_t* uoff  = (uint32_t*)nxt((size_t)(BUK + 1) * 4);
  uint32_t* bkt   = (uint32_t*)nxt((size_t)BUK * CAP * 4);  // ~21.6 MB

  int ablocks = (M + CH - 1) / CH;  // 782

  hipMemsetAsync(cur_g, 0, (size_t)BUK * 4, stream);
  passA_k<<<ablocks, 512, 0, stream>>>(a0, an, e0, en, pp, cur_g, bkt);
  passB_k<<<BUK, 512, 0, stream>>>(bkt, cur_g, ucnt);
  uscan_k<<<1, 64, 0, stream>>>(ucnt, uoff);
  passCT_k<<<BUK, 256, 0, stream>>>(bkt, uoff, (int*)d_out, oute);
}

// Round 20
// 106.840 us; speedup vs baseline: 1.0525x; 1.0047x over previous
//
#include <hip/hip_runtime.h>
#include <stdint.h>

#define BUK 782        // ceil(100000 / 128) src buckets
#define CAP 6912       // per-bucket region capacity (mean ~6246)
#define CH  8192       // edges per passA block (R17-validated sweet spot)
#define SENTK 0xFFFFFFFFu

__device__ __forceinline__ uint32_t rotl32(uint32_t x, int r) { return (x << r) | (x >> (32 - r)); }

// JAX threefry2x32, key=(0,42), counts x=(0,i); partitionable bits = out0^out1  (validated absmax=0)
__device__ __forceinline__ uint32_t threefry_bits(uint32_t i) {
  const uint32_t k0 = 0u, k1 = 42u;
  const uint32_t k2 = k0 ^ k1 ^ 0x1BD11BDAu;
  uint32_t x0 = k0;
  uint32_t x1 = i + k1;
#define TF_R(r) { x0 += x1; x1 = rotl32(x1, r); x1 ^= x0; }
  TF_R(13) TF_R(15) TF_R(26) TF_R(6)   x0 += k1; x1 += k2 + 1u;
  TF_R(17) TF_R(29) TF_R(16) TF_R(24)  x0 += k2; x1 += k0 + 2u;
  TF_R(13) TF_R(15) TF_R(26) TF_R(6)   x0 += k0; x1 += k1 + 3u;
  TF_R(17) TF_R(29) TF_R(16) TF_R(24)  x0 += k1; x1 += k2 + 4u;
  TF_R(13) TF_R(15) TF_R(26) TF_R(6)   x0 += k2; x1 += k0 + 5u;
#undef TF_R
  return x0 ^ x1;
}

__device__ __forceinline__ bool keep_edge(uint32_t i, float kp) {
  uint32_t bits = threefry_bits(i);
  float u = __uint_as_float((bits >> 9) | 0x3f800000u) - 1.0f;
  return u < kp;
}

__device__ __forceinline__ float keep_prob(const float* pp) {
  double pd = (double)pp[0];
  return (float)(1.0 / (1.0 + exp(-pd)));
}

// inclusive wave scan (64 lanes) via shfl_up
__device__ __forceinline__ uint32_t wave_incl_scan(uint32_t v, int lane) {
#pragma unroll
  for (int off = 1; off < 64; off <<= 1) {
    uint32_t t = (uint32_t)__shfl_up((int)v, off, 64);
    if (lane >= off) v += t;
  }
  return v;
}

// ---- VALU-pipe xor-shuffle: DPP for j<16, ds for 16/32 ----
template <int J>
__device__ __forceinline__ uint32_t xshf(uint32_t v, int lane) {
  if constexpr (J == 1) {
    return (uint32_t)__builtin_amdgcn_mov_dpp((int)v, 0xB1, 0xF, 0xF, true);  // quad_perm(1,0,3,2)
  } else if constexpr (J == 2) {
    return (uint32_t)__builtin_amdgcn_mov_dpp((int)v, 0x4E, 0xF, 0xF, true);  // quad_perm(2,3,0,1)
  } else if constexpr (J == 4 || J == 8) {
    uint32_t up = (uint32_t)__builtin_amdgcn_mov_dpp((int)v, 0x100 | J, 0xF, 0xF, true);
    uint32_t dn = (uint32_t)__builtin_amdgcn_mov_dpp((int)v, 0x110 | J, 0xF, 0xF, true);
    return (lane & J) ? dn : up;
  } else {
    return (uint32_t)__shfl_xor((int)v, J, 64);
  }
}

__device__ __forceinline__ void cex(uint32_t& v, uint32_t o, bool takeMin) {
  uint32_t mn = v < o ? v : o, mx = v < o ? o : v;
  v = takeMin ? mn : mx;
}
template <int J>
__device__ __forceinline__ void ce1(uint32_t& v, bool takeMin, int lane) {
  cex(v, xshf<J>(v, lane), takeMin);
}

__device__ __forceinline__ uint32_t bitonic64(uint32_t v, int lane) {
#define BS1(J, K) ce1<J>(v, ((lane & (J)) == 0) == ((lane & (K)) == 0), lane)
  BS1(1, 2);
  BS1(2, 4); BS1(1, 4);
  BS1(4, 8); BS1(2, 8); BS1(1, 8);
  BS1(8, 16); BS1(4, 16); BS1(2, 16); BS1(1, 16);
  BS1(16, 32); BS1(8, 32); BS1(4, 32); BS1(2, 32); BS1(1, 32);
  ce1<32>(v, (lane & 32) == 0, lane); ce1<16>(v, (lane & 16) == 0, lane);
  ce1<8>(v, (lane & 8) == 0, lane);   ce1<4>(v, (lane & 4) == 0, lane);
  ce1<2>(v, (lane & 2) == 0, lane);   ce1<1>(v, (lane & 1) == 0, lane);
#undef BS1
  return v;
}

__device__ __forceinline__ void bitonic128(uint32_t& v0, uint32_t& v1, int lane) {
#define BS2(J, K) { bool tm = ((lane & (J)) == 0) == ((lane & (K)) == 0); ce1<J>(v0, tm, lane); ce1<J>(v1, tm, lane); }
  BS2(1, 2);
  BS2(2, 4); BS2(1, 4);
  BS2(4, 8); BS2(2, 8); BS2(1, 8);
  BS2(8, 16); BS2(4, 16); BS2(2, 16); BS2(1, 16);
  BS2(16, 32); BS2(8, 32); BS2(4, 32); BS2(2, 32); BS2(1, 32);
#undef BS2
  ce1<32>(v0, (lane & 32) == 0, lane); ce1<32>(v1, (lane & 32) != 0, lane);
  ce1<16>(v0, (lane & 16) == 0, lane); ce1<16>(v1, (lane & 16) != 0, lane);
  ce1<8>(v0, (lane & 8) == 0, lane);   ce1<8>(v1, (lane & 8) != 0, lane);
  ce1<4>(v0, (lane & 4) == 0, lane);   ce1<4>(v1, (lane & 4) != 0, lane);
  ce1<2>(v0, (lane & 2) == 0, lane);   ce1<2>(v1, (lane & 2) != 0, lane);
  ce1<1>(v0, (lane & 1) == 0, lane);   ce1<1>(v1, (lane & 1) != 0, lane);
  { uint32_t lo = v0 < v1 ? v0 : v1, hi = v0 < v1 ? v1 : v0; v0 = lo; v1 = hi; }
  ce1<32>(v0, (lane & 32) == 0, lane); ce1<32>(v1, (lane & 32) == 0, lane);
  ce1<16>(v0, (lane & 16) == 0, lane); ce1<16>(v1, (lane & 16) == 0, lane);
  ce1<8>(v0, (lane & 8) == 0, lane);   ce1<8>(v1, (lane & 8) == 0, lane);
  ce1<4>(v0, (lane & 4) == 0, lane);   ce1<4>(v1, (lane & 4) == 0, lane);
  ce1<2>(v0, (lane & 2) == 0, lane);   ce1<2>(v1, (lane & 2) == 0, lane);
  ce1<1>(v0, (lane & 1) == 0, lane);   ce1<1>(v1, (lane & 1) == 0, lane);
}

// ---- pass A: LITERAL R17-validated v2 (56-57us, WRITE ~35MB) ----
__global__ __launch_bounds__(512) void passA_k(const int* __restrict__ a0,
                                               const int* __restrict__ an,
                                               int e0, int en, const float* __restrict__ pp,
                                               uint32_t* __restrict__ cur_g,
                                               uint32_t* __restrict__ bkt) {
  __shared__ uint32_t stageK[CH];
  __shared__ uint16_t stageB[CH];
  __shared__ uint32_t cntA[784];
  __shared__ uint32_t loA[784];
  __shared__ uint32_t gb[784];
  __shared__ uint32_t sums[512];

  float kp = keep_prob(pp);
  int tid = threadIdx.x;
  int total = e0 + en;
  int base = blockIdx.x * CH;

  uint32_t key[16];
  uint32_t bkid[16];

  for (int t = tid; t < 784; t += 512) cntA[t] = 0;
  __syncthreads();

  // phase 1: 4 groups of 4 consecutive edges per thread, int4 loads + LDS histogram
#pragma unroll
  for (int k = 0; k < 4; k++) {
    int g = base + 4 * (k * 512 + tid);
    int s4[4], d4[4];
    bool have = false;
    if (g + 3 < e0) {
      int4 sv = *reinterpret_cast<const int4*>(&a0[g]);
      int4 dv = *reinterpret_cast<const int4*>(&a0[e0 + g]);
      s4[0] = sv.x; s4[1] = sv.y; s4[2] = sv.z; s4[3] = sv.w;
      d4[0] = dv.x; d4[1] = dv.y; d4[2] = dv.z; d4[3] = dv.w;
      have = true;
    } else if (g >= e0 && g + 3 < total) {
      int j = g - e0;
      int4 sv = *reinterpret_cast<const int4*>(&an[j]);
      int4 dv = *reinterpret_cast<const int4*>(&an[en + j]);
      s4[0] = sv.x; s4[1] = sv.y; s4[2] = sv.z; s4[3] = sv.w;
      d4[0] = dv.x; d4[1] = dv.y; d4[2] = dv.z; d4[3] = dv.w;
      have = true;
    } else if (g < total) {
      for (int e = 0; e < 4; e++) {
        int idx = g + e;
        if (idx < total) {
          if (idx < e0) { s4[e] = a0[idx]; d4[e] = a0[e0 + idx]; }
          else          { int j = idx - e0; s4[e] = an[j]; d4[e] = an[en + j]; }
        } else { s4[e] = -1; d4[e] = 0; }
      }
      have = true;
    }
#pragma unroll
    for (int e = 0; e < 4; e++) {
      int idx = g + e;
      uint32_t ky = SENTK, b_ = SENTK;
      if (have && idx < total && s4[e] >= 0) {
        bool keep = (idx < e0) ? keep_edge((uint32_t)idx, kp) : true;
        if (keep) {
          uint32_t us = (uint32_t)s4[e];
          b_ = us >> 7;
          if (b_ < BUK) ky = ((us & 127u) << 17) | (uint32_t)d4[e];
          else b_ = SENTK;
        }
      }
      key[k * 4 + e] = ky;
      bkid[k * 4 + e] = b_;
      if (b_ != SENTK) atomicAdd(&cntA[b_], 1u);
    }
  }
  __syncthreads();

  // phase 2: exclusive scan over 784 bins (pairs -> 392 sums, Hillis over 512)
  {
    uint32_t s2 = 0;
    if (tid < 392) s2 = cntA[2 * tid] + cntA[2 * tid + 1];
    sums[tid] = s2;
    __syncthreads();
    for (int off = 1; off < 512; off <<= 1) {
      uint32_t a = (tid >= off) ? sums[tid - off] : 0u;
      __syncthreads();
      sums[tid] += a;
      __syncthreads();
    }
    if (tid < 392) {
      uint32_t b0 = sums[tid] - s2;
      loA[2 * tid] = b0;
      loA[2 * tid + 1] = b0 + cntA[2 * tid];
    }
  }
  __syncthreads();
  for (int t = tid; t < 784; t += 512) gb[t] = loA[t];
  __syncthreads();

  // phase 3: LDS counting-scatter into bucket-major staging
#pragma unroll
  for (int k = 0; k < 16; k++) {
    uint32_t b_ = bkid[k];
    if (b_ != SENTK) {
      uint32_t p = atomicAdd(&gb[b_], 1u);
      stageK[p] = key[k];
      stageB[p] = (uint16_t)b_;
    }
  }
  __syncthreads();

  // phase 4: per-bucket global reservation (unpadded)
  for (int t = tid; t < BUK; t += 512) {
    uint32_t c = cntA[t];
    gb[t] = c ? atomicAdd(&cur_g[t], c) : 0u;
  }
  __syncthreads();

  // phase 5: staged-order cooperative flush (coalesced bucket runs)
  uint32_t kept = sums[511];
  for (uint32_t i = tid; i < kept; i += 512) {
    uint32_t b_ = (uint32_t)stageB[i];
    uint32_t addr = gb[b_] + (i - loA[b_]);
    if (addr < CAP) bkt[(size_t)b_ * CAP + addr] = stageK[i];
  }
}

// ---- pass B v5 (R17-validated ~39us): uint4 read -> regs; reg hist+scatter; DPP-bitonic; dedup ----
__global__ __launch_bounds__(512) void passB_k(uint32_t* __restrict__ bkt,
                                               const uint32_t* __restrict__ cur_g,
                                               uint32_t* __restrict__ ucnt) {
  __shared__ uint32_t lin[CAP];                 // 27 KB
  __shared__ uint32_t c128[128], lo128[128], cur128[128];
  __shared__ uint32_t u128[128], uo128[128];

  int b = blockIdx.x, tid = threadIdx.x;
  int wid = tid >> 6, lane = tid & 63;
  uint32_t len = cur_g[b];
  if (len > CAP) len = CAP;
  uint32_t* seg = bkt + (size_t)b * CAP;

  if (tid < 128) c128[tid] = 0;
  __syncthreads();

  // single vectorized read into registers (<= 16 values/thread)
  uint32_t rv[16];
#pragma unroll
  for (int k = 0; k < 4; k++) {
    uint32_t i4 = 4u * (uint32_t)(k * 512 + tid);
    if (i4 + 3 < len) {
      uint4 v = *reinterpret_cast<const uint4*>(&seg[i4]);
      rv[4 * k] = v.x; rv[4 * k + 1] = v.y; rv[4 * k + 2] = v.z; rv[4 * k + 3] = v.w;
    } else {
#pragma unroll
      for (int e = 0; e < 4; e++) rv[4 * k + e] = (i4 + e < len) ? seg[i4 + e] : SENTK;
    }
  }

  // histogram from registers
#pragma unroll
  for (int k = 0; k < 16; k++)
    if (rv[k] != SENTK) atomicAdd(&c128[rv[k] >> 17], 1u);
  __syncthreads();

  // wave-0 shuffle scan of 128 counts -> lo128/cur128 (exclusive)
  if (wid == 0) {
    uint32_t c0 = c128[2 * lane], c1 = c128[2 * lane + 1];
    uint32_t s = c0 + c1;
    uint32_t inc = wave_incl_scan(s, lane);
    uint32_t ex = inc - s;
    lo128[2 * lane] = ex;       lo128[2 * lane + 1] = ex + c0;
    cur128[2 * lane] = ex;      cur128[2 * lane + 1] = ex + c0;
  }
  __syncthreads();

  // counting-scatter from registers
#pragma unroll
  for (int k = 0; k < 16; k++)
    if (rv[k] != SENTK) lin[atomicAdd(&cur128[rv[k] >> 17], 1u)] = rv[k];
  __syncthreads();

  // per-wave sub-bin sort + dedup-compact (regions disjoint across waves)
  for (int s = wid; s < 128; s += 8) {
    uint32_t L = c128[s], sb = lo128[s];
    if (L > 1u && L <= 64u) {
      uint32_t v = (lane < (int)L) ? lin[sb + lane] : SENTK;
      v = bitonic64(v, lane);
      if (lane < (int)L) lin[sb + lane] = v;
    } else if (L > 64u && L <= 128u) {
      uint32_t v0 = (lane < (int)L) ? lin[sb + lane] : SENTK;
      uint32_t v1 = (64 + lane < (int)L) ? lin[sb + 64 + lane] : SENTK;
      bitonic128(v0, v1, lane);
      if (lane < (int)L) lin[sb + lane] = v0;
      if (64 + lane < (int)L) lin[sb + 64 + lane] = v1;
    } else if (L > 128u) {
      // never expected (mean 48.8); rank-sort via dead global seg region
      uint32_t* gsc = seg + sb;
      for (uint32_t i0 = lane; i0 < L; i0 += 64) {
        uint32_t x = lin[sb + i0];
        uint32_t pos = 0;
        for (uint32_t j = 0; j < L; j++) {
          uint32_t y = lin[sb + j];
          pos += (y < x || (y == x && j < i0)) ? 1u : 0u;
        }
        gsc[pos] = x;
      }
      asm volatile("s_waitcnt vmcnt(0)" ::: "memory");
      for (uint32_t i0 = lane; i0 < L; i0 += 64) lin[sb + i0] = gsc[i0];
    }
    // dedup-compact within sub-bin
    uint32_t ub = 0;
    for (uint32_t t = 0; t < L; t += 64) {
      uint32_t i = t + lane;
      bool valid = i < L;
      uint32_t x = valid ? lin[sb + i] : 0u;
      uint32_t prev = valid ? lin[sb + (i == 0 ? 0 : i - 1)] : 0u;
      bool uniq = valid && (i == 0 || prev != x);
      unsigned long long ball = __ballot(uniq ? 1 : 0);
      uint32_t rank = (uint32_t)__popcll(ball & ((1ull << lane) - 1ull));
      if (uniq) lin[sb + ub + rank] = x;
      ub += (uint32_t)__popcll(ball);
    }
    if (lane == 0) u128[s] = ub;
  }
  __syncthreads();

  // wave-0 shuffle scan of unique counts -> uo128 (exclusive) + ucnt[b]
  if (wid == 0) {
    uint32_t c0 = u128[2 * lane], c1 = u128[2 * lane + 1];
    uint32_t s = c0 + c1;
    uint32_t inc = wave_incl_scan(s, lane);
    uint32_t ex = inc - s;
    uo128[2 * lane] = ex;       uo128[2 * lane + 1] = ex + c0;
    if (lane == 63) ucnt[b] = inc;
  }
  __syncthreads();

  // copy compacted uniques to seg front (sub-bin order = key order)
  for (int s = wid; s < 128; s += 8) {
    uint32_t u = u128[s], sb = lo128[s], ob = uo128[s];
    for (uint32_t k2 = lane; k2 < u; k2 += 64) seg[ob + k2] = lin[sb + k2];
  }
}

// ---- pass C+tail with inline prefix computation (uscan fused away) ----
__global__ __launch_bounds__(256) void passCT_k(const uint32_t* __restrict__ bkt,
                                                const uint32_t* __restrict__ ucnt,
                                                int* __restrict__ out, int oute) {
  __shared__ uint32_t wall[4], wpre[4];
  int b = blockIdx.x, tid = threadIdx.x;
  int wid = tid >> 6, lane = tid & 63;

  // each block computes total = sum(ucnt) and lo = sum(ucnt[0..b)) from L2-resident ucnt
  uint32_t t_all = 0, t_pre = 0;
  for (int i = tid; i < BUK; i += 256) {
    uint32_t c = ucnt[i];
    t_all += c;
    if (i < b) t_pre += c;
  }
#pragma unroll
  for (int off = 32; off >= 1; off >>= 1) {
    t_all += (uint32_t)__shfl_xor((int)t_all, off, 64);
    t_pre += (uint32_t)__shfl_xor((int)t_pre, off, 64);
  }
  if (lane == 0) { wall[wid] = t_all; wpre[wid] = t_pre; }
  __syncthreads();
  uint32_t total = wall[0] + wall[1] + wall[2] + wall[3];
  uint32_t lo = wpre[0] + wpre[1] + wpre[2] + wpre[3];
  uint32_t u = ucnt[b];

  const uint32_t* seg = bkt + (size_t)b * CAP;
  for (uint32_t k = tid; k < u; k += 256) {
    uint32_t key = seg[k];
    out[lo + k] = (int)((uint32_t)(b << 7) | (key >> 17));
    out[oute + lo + k] = (int)(key & 0x1FFFFu);
  }
  // tail fill: all blocks grid-stride the invalid region [total, oute)
  for (uint32_t i = (uint32_t)b * 256u + (uint32_t)tid + total; i < (uint32_t)oute;
       i += (uint32_t)gridDim.x * 256u) {
    out[i] = -1;
    out[oute + i] = -1;
  }
}

extern "C" void kernel_launch(void* const* d_in, const int* in_sizes, int n_in,
                              void* d_out, int out_size, void* d_ws, size_t ws_size,
                              hipStream_t stream) {
  const int* a0 = (const int*)d_in[0];
  const int* an = (const int*)d_in[1];
  const float* pp = (const float*)d_in[3];
  int e0 = in_sizes[0] / 2;
  int en = in_sizes[1] / 2;
  int M = e0 + en;
  int oute = out_size / 2;

  uint8_t* wbase = (uint8_t*)d_ws;
  size_t o = 0;
  auto nxt = [&](size_t bytes) -> void* {
    void* p = wbase + o;
    o = (o + bytes + 255) & ~(size_t)255;
    return p;
  };
  uint32_t* cur_g = (uint32_t*)nxt((size_t)BUK * 4);
  uint32_t* ucnt  = (uint32_t*)nxt((size_t)BUK * 4);
  uint32_t* bkt   = (uint32_t*)nxt((size_t)BUK * CAP * 4);  // ~21.6 MB

  int ablocks = (M + CH - 1) / CH;  // 782

  hipMemsetAsync(cur_g, 0, (size_t)BUK * 4, stream);
  passA_k<<<ablocks, 512, 0, stream>>>(a0, an, e0, en, pp, cur_g, bkt);
  passB_k<<<BUK, 512, 0, stream>>>(bkt, cur_g, ucnt);
  passCT_k<<<BUK, 256, 0, stream>>>(bkt, ucnt, (int*)d_out, oute);
}

// Round 21
// 104.831 us; speedup vs baseline: 1.0727x; 1.0192x over previous
//
#include <hip/hip_runtime.h>
#include <stdint.h>

#define BUK 782        // ceil(100000 / 128) src buckets
#define CAP 6912       // per-bucket region capacity (mean ~6246)
#define CH  8192       // edges per passA block (R17-validated sweet spot)
#define SENTK 0xFFFFFFFFu

__device__ __forceinline__ uint32_t rotl32(uint32_t x, int r) { return (x << r) | (x >> (32 - r)); }

// JAX threefry2x32, key=(0,42), counts x=(0,i); partitionable bits = out0^out1  (validated absmax=0)
__device__ __forceinline__ uint32_t threefry_bits(uint32_t i) {
  const uint32_t k0 = 0u, k1 = 42u;
  const uint32_t k2 = k0 ^ k1 ^ 0x1BD11BDAu;
  uint32_t x0 = k0;
  uint32_t x1 = i + k1;
#define TF_R(r) { x0 += x1; x1 = rotl32(x1, r); x1 ^= x0; }
  TF_R(13) TF_R(15) TF_R(26) TF_R(6)   x0 += k1; x1 += k2 + 1u;
  TF_R(17) TF_R(29) TF_R(16) TF_R(24)  x0 += k2; x1 += k0 + 2u;
  TF_R(13) TF_R(15) TF_R(26) TF_R(6)   x0 += k0; x1 += k1 + 3u;
  TF_R(17) TF_R(29) TF_R(16) TF_R(24)  x0 += k1; x1 += k2 + 4u;
  TF_R(13) TF_R(15) TF_R(26) TF_R(6)   x0 += k2; x1 += k0 + 5u;
#undef TF_R
  return x0 ^ x1;
}

__device__ __forceinline__ bool keep_edge(uint32_t i, float kp) {
  uint32_t bits = threefry_bits(i);
  float u = __uint_as_float((bits >> 9) | 0x3f800000u) - 1.0f;
  return u < kp;
}

__device__ __forceinline__ float keep_prob(const float* pp) {
  double pd = (double)pp[0];
  return (float)(1.0 / (1.0 + exp(-pd)));
}

// inclusive wave scan (64 lanes) via shfl_up
__device__ __forceinline__ uint32_t wave_incl_scan(uint32_t v, int lane) {
#pragma unroll
  for (int off = 1; off < 64; off <<= 1) {
    uint32_t t = (uint32_t)__shfl_up((int)v, off, 64);
    if (lane >= off) v += t;
  }
  return v;
}

// ---- VALU-pipe xor-shuffle: DPP for j<16, ds for 16/32 ----
template <int J>
__device__ __forceinline__ uint32_t xshf(uint32_t v, int lane) {
  if constexpr (J == 1) {
    return (uint32_t)__builtin_amdgcn_mov_dpp((int)v, 0xB1, 0xF, 0xF, true);  // quad_perm(1,0,3,2)
  } else if constexpr (J == 2) {
    return (uint32_t)__builtin_amdgcn_mov_dpp((int)v, 0x4E, 0xF, 0xF, true);  // quad_perm(2,3,0,1)
  } else if constexpr (J == 4 || J == 8) {
    uint32_t up = (uint32_t)__builtin_amdgcn_mov_dpp((int)v, 0x100 | J, 0xF, 0xF, true);
    uint32_t dn = (uint32_t)__builtin_amdgcn_mov_dpp((int)v, 0x110 | J, 0xF, 0xF, true);
    return (lane & J) ? dn : up;
  } else {
    return (uint32_t)__shfl_xor((int)v, J, 64);
  }
}

__device__ __forceinline__ void cex(uint32_t& v, uint32_t o, bool takeMin) {
  uint32_t mn = v < o ? v : o, mx = v < o ? o : v;
  v = takeMin ? mn : mx;
}
template <int J>
__device__ __forceinline__ void ce1(uint32_t& v, bool takeMin, int lane) {
  cex(v, xshf<J>(v, lane), takeMin);
}

__device__ __forceinline__ uint32_t bitonic64(uint32_t v, int lane) {
#define BS1(J, K) ce1<J>(v, ((lane & (J)) == 0) == ((lane & (K)) == 0), lane)
  BS1(1, 2);
  BS1(2, 4); BS1(1, 4);
  BS1(4, 8); BS1(2, 8); BS1(1, 8);
  BS1(8, 16); BS1(4, 16); BS1(2, 16); BS1(1, 16);
  BS1(16, 32); BS1(8, 32); BS1(4, 32); BS1(2, 32); BS1(1, 32);
  ce1<32>(v, (lane & 32) == 0, lane); ce1<16>(v, (lane & 16) == 0, lane);
  ce1<8>(v, (lane & 8) == 0, lane);   ce1<4>(v, (lane & 4) == 0, lane);
  ce1<2>(v, (lane & 2) == 0, lane);   ce1<1>(v, (lane & 1) == 0, lane);
#undef BS1
  return v;
}

__device__ __forceinline__ void bitonic128(uint32_t& v0, uint32_t& v1, int lane) {
#define BS2(J, K) { bool tm = ((lane & (J)) == 0) == ((lane & (K)) == 0); ce1<J>(v0, tm, lane); ce1<J>(v1, tm, lane); }
  BS2(1, 2);
  BS2(2, 4); BS2(1, 4);
  BS2(4, 8); BS2(2, 8); BS2(1, 8);
  BS2(8, 16); BS2(4, 16); BS2(2, 16); BS2(1, 16);
  BS2(16, 32); BS2(8, 32); BS2(4, 32); BS2(2, 32); BS2(1, 32);
#undef BS2
  ce1<32>(v0, (lane & 32) == 0, lane); ce1<32>(v1, (lane & 32) != 0, lane);
  ce1<16>(v0, (lane & 16) == 0, lane); ce1<16>(v1, (lane & 16) != 0, lane);
  ce1<8>(v0, (lane & 8) == 0, lane);   ce1<8>(v1, (lane & 8) != 0, lane);
  ce1<4>(v0, (lane & 4) == 0, lane);   ce1<4>(v1, (lane & 4) != 0, lane);
  ce1<2>(v0, (lane & 2) == 0, lane);   ce1<2>(v1, (lane & 2) != 0, lane);
  ce1<1>(v0, (lane & 1) == 0, lane);   ce1<1>(v1, (lane & 1) != 0, lane);
  { uint32_t lo = v0 < v1 ? v0 : v1, hi = v0 < v1 ? v1 : v0; v0 = lo; v1 = hi; }
  ce1<32>(v0, (lane & 32) == 0, lane); ce1<32>(v1, (lane & 32) == 0, lane);
  ce1<16>(v0, (lane & 16) == 0, lane); ce1<16>(v1, (lane & 16) == 0, lane);
  ce1<8>(v0, (lane & 8) == 0, lane);   ce1<8>(v1, (lane & 8) == 0, lane);
  ce1<4>(v0, (lane & 4) == 0, lane);   ce1<4>(v1, (lane & 4) == 0, lane);
  ce1<2>(v0, (lane & 2) == 0, lane);   ce1<2>(v1, (lane & 2) == 0, lane);
  ce1<1>(v0, (lane & 1) == 0, lane);   ce1<1>(v1, (lane & 1) == 0, lane);
}

// ---- pass A: R17 v2 structure; ONLY change: phase-2 Hillis -> wave-0 shuffle scan ----
__global__ __launch_bounds__(512) void passA_k(const int* __restrict__ a0,
                                               const int* __restrict__ an,
                                               int e0, int en, const float* __restrict__ pp,
                                               uint32_t* __restrict__ cur_g,
                                               uint32_t* __restrict__ bkt) {
  __shared__ uint32_t stageK[CH];
  __shared__ uint16_t stageB[CH];
  __shared__ uint32_t cntA[784];
  __shared__ uint32_t loA[784];
  __shared__ uint32_t gb[784];
  __shared__ uint32_t keptS;

  float kp = keep_prob(pp);
  int tid = threadIdx.x;
  int wid = tid >> 6, lane = tid & 63;
  int total = e0 + en;
  int base = blockIdx.x * CH;

  uint32_t key[16];
  uint32_t bkid[16];

  for (int t = tid; t < 784; t += 512) cntA[t] = 0;
  __syncthreads();

  // phase 1: 4 groups of 4 consecutive edges per thread, int4 loads + LDS histogram
#pragma unroll
  for (int k = 0; k < 4; k++) {
    int g = base + 4 * (k * 512 + tid);
    int s4[4], d4[4];
    bool have = false;
    if (g + 3 < e0) {
      int4 sv = *reinterpret_cast<const int4*>(&a0[g]);
      int4 dv = *reinterpret_cast<const int4*>(&a0[e0 + g]);
      s4[0] = sv.x; s4[1] = sv.y; s4[2] = sv.z; s4[3] = sv.w;
      d4[0] = dv.x; d4[1] = dv.y; d4[2] = dv.z; d4[3] = dv.w;
      have = true;
    } else if (g >= e0 && g + 3 < total) {
      int j = g - e0;
      int4 sv = *reinterpret_cast<const int4*>(&an[j]);
      int4 dv = *reinterpret_cast<const int4*>(&an[en + j]);
      s4[0] = sv.x; s4[1] = sv.y; s4[2] = sv.z; s4[3] = sv.w;
      d4[0] = dv.x; d4[1] = dv.y; d4[2] = dv.z; d4[3] = dv.w;
      have = true;
    } else if (g < total) {
      for (int e = 0; e < 4; e++) {
        int idx = g + e;
        if (idx < total) {
          if (idx < e0) { s4[e] = a0[idx]; d4[e] = a0[e0 + idx]; }
          else          { int j = idx - e0; s4[e] = an[j]; d4[e] = an[en + j]; }
        } else { s4[e] = -1; d4[e] = 0; }
      }
      have = true;
    }
#pragma unroll
    for (int e = 0; e < 4; e++) {
      int idx = g + e;
      uint32_t ky = SENTK, b_ = SENTK;
      if (have && idx < total && s4[e] >= 0) {
        bool keep = (idx < e0) ? keep_edge((uint32_t)idx, kp) : true;
        if (keep) {
          uint32_t us = (uint32_t)s4[e];
          b_ = us >> 7;
          if (b_ < BUK) ky = ((us & 127u) << 17) | (uint32_t)d4[e];
          else b_ = SENTK;
        }
      }
      key[k * 4 + e] = ky;
      bkid[k * 4 + e] = b_;
      if (b_ != SENTK) atomicAdd(&cntA[b_], 1u);
    }
  }
  __syncthreads();

  // phase 2: wave-0 shuffle scan over 784 bins -> loA (exclusive), gb (cursor), keptS
  if (wid == 0) {
    uint32_t c[13];
    uint32_t s = 0;
#pragma unroll
    for (int j = 0; j < 13; j++) {
      int idx = lane * 13 + j;
      c[j] = (idx < 784) ? cntA[idx] : 0u;
      s += c[j];
    }
    uint32_t inc = wave_incl_scan(s, lane);
    uint32_t ex = inc - s;
#pragma unroll
    for (int j = 0; j < 13; j++) {
      int idx = lane * 13 + j;
      if (idx < 784) { loA[idx] = ex; gb[idx] = ex; }
      ex += c[j];
    }
    if (lane == 63) keptS = ex;
  }
  __syncthreads();

  // phase 3: LDS counting-scatter into bucket-major staging
#pragma unroll
  for (int k = 0; k < 16; k++) {
    uint32_t b_ = bkid[k];
    if (b_ != SENTK) {
      uint32_t p = atomicAdd(&gb[b_], 1u);
      stageK[p] = key[k];
      stageB[p] = (uint16_t)b_;
    }
  }
  __syncthreads();

  // phase 4: per-bucket global reservation (unpadded, after scatter — R17 timing)
  for (int t = tid; t < BUK; t += 512) {
    uint32_t c = cntA[t];
    gb[t] = c ? atomicAdd(&cur_g[t], c) : 0u;
  }
  __syncthreads();

  // phase 5: staged-order cooperative flush (coalesced bucket runs)
  uint32_t kept = keptS;
  for (uint32_t i = tid; i < kept; i += 512) {
    uint32_t b_ = (uint32_t)stageB[i];
    uint32_t addr = gb[b_] + (i - loA[b_]);
    if (addr < CAP) bkt[(size_t)b_ * CAP + addr] = stageK[i];
  }
}

// ---- pass B v5 (R17-validated ~39us): uint4 read -> regs; reg hist+scatter; DPP-bitonic; dedup ----
__global__ __launch_bounds__(512) void passB_k(uint32_t* __restrict__ bkt,
                                               const uint32_t* __restrict__ cur_g,
                                               uint32_t* __restrict__ ucnt) {
  __shared__ uint32_t lin[CAP];                 // 27 KB
  __shared__ uint32_t c128[128], lo128[128], cur128[128];
  __shared__ uint32_t u128[128], uo128[128];

  int b = blockIdx.x, tid = threadIdx.x;
  int wid = tid >> 6, lane = tid & 63;
  uint32_t len = cur_g[b];
  if (len > CAP) len = CAP;
  uint32_t* seg = bkt + (size_t)b * CAP;

  if (tid < 128) c128[tid] = 0;
  __syncthreads();

  // single vectorized read into registers (<= 16 values/thread)
  uint32_t rv[16];
#pragma unroll
  for (int k = 0; k < 4; k++) {
    uint32_t i4 = 4u * (uint32_t)(k * 512 + tid);
    if (i4 + 3 < len) {
      uint4 v = *reinterpret_cast<const uint4*>(&seg[i4]);
      rv[4 * k] = v.x; rv[4 * k + 1] = v.y; rv[4 * k + 2] = v.z; rv[4 * k + 3] = v.w;
    } else {
#pragma unroll
      for (int e = 0; e < 4; e++) rv[4 * k + e] = (i4 + e < len) ? seg[i4 + e] : SENTK;
    }
  }

  // histogram from registers
#pragma unroll
  for (int k = 0; k < 16; k++)
    if (rv[k] != SENTK) atomicAdd(&c128[rv[k] >> 17], 1u);
  __syncthreads();

  // wave-0 shuffle scan of 128 counts -> lo128/cur128 (exclusive)
  if (wid == 0) {
    uint32_t c0 = c128[2 * lane], c1 = c128[2 * lane + 1];
    uint32_t s = c0 + c1;
    uint32_t inc = wave_incl_scan(s, lane);
    uint32_t ex = inc - s;
    lo128[2 * lane] = ex;       lo128[2 * lane + 1] = ex + c0;
    cur128[2 * lane] = ex;      cur128[2 * lane + 1] = ex + c0;
  }
  __syncthreads();

  // counting-scatter from registers
#pragma unroll
  for (int k = 0; k < 16; k++)
    if (rv[k] != SENTK) lin[atomicAdd(&cur128[rv[k] >> 17], 1u)] = rv[k];
  __syncthreads();

  // per-wave sub-bin sort + dedup-compact (regions disjoint across waves)
  for (int s = wid; s < 128; s += 8) {
    uint32_t L = c128[s], sb = lo128[s];
    if (L > 1u && L <= 64u) {
      uint32_t v = (lane < (int)L) ? lin[sb + lane] : SENTK;
      v = bitonic64(v, lane);
      if (lane < (int)L) lin[sb + lane] = v;
    } else if (L > 64u && L <= 128u) {
      uint32_t v0 = (lane < (int)L) ? lin[sb + lane] : SENTK;
      uint32_t v1 = (64 + lane < (int)L) ? lin[sb + 64 + lane] : SENTK;
      bitonic128(v0, v1, lane);
      if (lane < (int)L) lin[sb + lane] = v0;
      if (64 + lane < (int)L) lin[sb + 64 + lane] = v1;
    } else if (L > 128u) {
      // never expected (mean 48.8); rank-sort via dead global seg region
      uint32_t* gsc = seg + sb;
      for (uint32_t i0 = lane; i0 < L; i0 += 64) {
        uint32_t x = lin[sb + i0];
        uint32_t pos = 0;
        for (uint32_t j = 0; j < L; j++) {
          uint32_t y = lin[sb + j];
          pos += (y < x || (y == x && j < i0)) ? 1u : 0u;
        }
        gsc[pos] = x;
      }
      asm volatile("s_waitcnt vmcnt(0)" ::: "memory");
      for (uint32_t i0 = lane; i0 < L; i0 += 64) lin[sb + i0] = gsc[i0];
    }
    // dedup-compact within sub-bin
    uint32_t ub = 0;
    for (uint32_t t = 0; t < L; t += 64) {
      uint32_t i = t + lane;
      bool valid = i < L;
      uint32_t x = valid ? lin[sb + i] : 0u;
      uint32_t prev = valid ? lin[sb + (i == 0 ? 0 : i - 1)] : 0u;
      bool uniq = valid && (i == 0 || prev != x);
      unsigned long long ball = __ballot(uniq ? 1 : 0);
      uint32_t rank = (uint32_t)__popcll(ball & ((1ull << lane) - 1ull));
      if (uniq) lin[sb + ub + rank] = x;
      ub += (uint32_t)__popcll(ball);
    }
    if (lane == 0) u128[s] = ub;
  }
  __syncthreads();

  // wave-0 shuffle scan of unique counts -> uo128 (exclusive) + ucnt[b]
  if (wid == 0) {
    uint32_t c0 = u128[2 * lane], c1 = u128[2 * lane + 1];
    uint32_t s = c0 + c1;
    uint32_t inc = wave_incl_scan(s, lane);
    uint32_t ex = inc - s;
    uo128[2 * lane] = ex;       uo128[2 * lane + 1] = ex + c0;
    if (lane == 63) ucnt[b] = inc;
  }
  __syncthreads();

  // copy compacted uniques to seg front (sub-bin order = key order)
  for (int s = wid; s < 128; s += 8) {
    uint32_t u = u128[s], sb = lo128[s], ob = uo128[s];
    for (uint32_t k2 = lane; k2 < u; k2 += 64) seg[ob + k2] = lin[sb + k2];
  }
}

// ---- pass C+tail with inline prefix computation (R20-validated) ----
__global__ __launch_bounds__(256) void passCT_k(const uint32_t* __restrict__ bkt,
                                                const uint32_t* __restrict__ ucnt,
                                                int* __restrict__ out, int oute) {
  __shared__ uint32_t wall[4], wpre[4];
  int b = blockIdx.x, tid = threadIdx.x;
  int wid = tid >> 6, lane = tid & 63;

  // each block computes total = sum(ucnt) and lo = sum(ucnt[0..b)) from L2-resident ucnt
  uint32_t t_all = 0, t_pre = 0;
  for (int i = tid; i < BUK; i += 256) {
    uint32_t c = ucnt[i];
    t_all += c;
    if (i < b) t_pre += c;
  }
#pragma unroll
  for (int off = 32; off >= 1; off >>= 1) {
    t_all += (uint32_t)__shfl_xor((int)t_all, off, 64);
    t_pre += (uint32_t)__shfl_xor((int)t_pre, off, 64);
  }
  if (lane == 0) { wall[wid] = t_all; wpre[wid] = t_pre; }
  __syncthreads();
  uint32_t total = wall[0] + wall[1] + wall[2] + wall[3];
  uint32_t lo = wpre[0] + wpre[1] + wpre[2] + wpre[3];
  uint32_t u = ucnt[b];

  const uint32_t* seg = bkt + (size_t)b * CAP;
  for (uint32_t k = tid; k < u; k += 256) {
    uint32_t key = seg[k];
    out[lo + k] = (int)((uint32_t)(b << 7) | (key >> 17));
    out[oute + lo + k] = (int)(key & 0x1FFFFu);
  }
  // tail fill: all blocks grid-stride the invalid region [total, oute)
  for (uint32_t i = (uint32_t)b * 256u + (uint32_t)tid + total; i < (uint32_t)oute;
       i += (uint32_t)gridDim.x * 256u) {
    out[i] = -1;
    out[oute + i] = -1;
  }
}

extern "C" void kernel_launch(void* const* d_in, const int* in_sizes, int n_in,
                              void* d_out, int out_size, void* d_ws, size_t ws_size,
                              hipStream_t stream) {
  const int* a0 = (const int*)d_in[0];
  const int* an = (const int*)d_in[1];
  const float* pp = (const float*)d_in[3];
  int e0 = in_sizes[0] / 2;
  int en = in_sizes[1] / 2;
  int M = e0 + en;
  int oute = out_size / 2;

  uint8_t* wbase = (uint8_t*)d_ws;
  size_t o = 0;
  auto nxt = [&](size_t bytes) -> void* {
    void* p = wbase + o;
    o = (o + bytes + 255) & ~(size_t)255;
    return p;
  };
  uint32_t* cur_g = (uint32_t*)nxt((size_t)BUK * 4);
  uint32_t* ucnt  = (uint32_t*)nxt((size_t)BUK * 4);
  uint32_t* bkt   = (uint32_t*)nxt((size_t)BUK * CAP * 4);  // ~21.6 MB

  int ablocks = (M + CH - 1) / CH;  // 782

  hipMemsetAsync(cur_g, 0, (size_t)BUK * 4, stream);
  passA_k<<<ablocks, 512, 0, stream>>>(a0, an, e0, en, pp, cur_g, bkt);
  passB_k<<<BUK, 512, 0, stream>>>(bkt, cur_g, ucnt);
  passCT_k<<<BUK, 256, 0, stream>>>(bkt, ucnt, (int*)d_out, oute);
}